// Round 8
// baseline (508.566 us; speedup 1.0000x reference)
//
#include <hip/hip_runtime.h>
#include <cmath>

namespace {

constexpr int B_ = 2;
constexpr int T_ = 2048;
constexpr int C_ = 1024;
constexpr int H_ = 16;
constexpr int D_ = 64;

typedef _Float16 half8 __attribute__((ext_vector_type(8)));
typedef _Float16 half4 __attribute__((ext_vector_type(4)));
typedef float f32x4 __attribute__((ext_vector_type(4)));

__device__ inline f32x4 vmax4(f32x4 a, f32x4 b) {
  f32x4 r;
  r[0] = fmaxf(a[0], b[0]); r[1] = fmaxf(a[1], b[1]);
  r[2] = fmaxf(a[2], b[2]); r[3] = fmaxf(a[3], b[3]);
  return r;
}

__device__ __forceinline__ void gload16(const _Float16* g, _Float16* l) {
  __builtin_amdgcn_global_load_lds(
      (const __attribute__((address_space(1))) unsigned int*)g,
      (__attribute__((address_space(3))) unsigned int*)l, 16, 0, 0);
}

// ---------------------------------------------------------------------------
// Fused cast: 7 fp32 arrays -> f16 (xq,xk,xv: 4M els; Wq,Wk,Wv,Wo: 1M els).
// ---------------------------------------------------------------------------
__global__ __launch_bounds__(256)
void cast7(const float* __restrict__ xq, const float* __restrict__ xk,
           const float* __restrict__ xv, const float* __restrict__ wq,
           const float* __restrict__ wk, const float* __restrict__ wv,
           const float* __restrict__ wo,
           _Float16* __restrict__ dxq, _Float16* __restrict__ dxk,
           _Float16* __restrict__ dxv, _Float16* __restrict__ dwq,
           _Float16* __restrict__ dwk, _Float16* __restrict__ dwv,
           _Float16* __restrict__ dwo) {
  constexpr size_t NX = (size_t)4 << 20;
  constexpr size_t NW = (size_t)1 << 20;
  size_t g = ((size_t)blockIdx.x * 256 + threadIdx.x) * 8;
  const float* s; _Float16* d; size_t off;
  if      (g <     NX)          { s = xq; d = dxq; off = g; }
  else if (g < 2 * NX)          { s = xk; d = dxk; off = g - NX; }
  else if (g < 3 * NX)          { s = xv; d = dxv; off = g - 2 * NX; }
  else if (g < 3 * NX + NW)     { s = wq; d = dwq; off = g - 3 * NX; }
  else if (g < 3 * NX + 2 * NW) { s = wk; d = dwk; off = g - 3 * NX - NW; }
  else if (g < 3 * NX + 3 * NW) { s = wv; d = dwv; off = g - 3 * NX - 2 * NW; }
  else                          { s = wo; d = dwo; off = g - 3 * NX - 3 * NW; }
  const float4 a = *(const float4*)(s + off);
  const float4 b = *(const float4*)(s + off + 4);
  half8 h;
  h[0] = (_Float16)a.x; h[1] = (_Float16)a.y; h[2] = (_Float16)a.z; h[3] = (_Float16)a.w;
  h[4] = (_Float16)b.x; h[5] = (_Float16)b.y; h[6] = (_Float16)b.z; h[7] = (_Float16)b.w;
  *(half8*)(d + off) = h;
}

// ---------------------------------------------------------------------------
// LDS-staged f16 NT GEMM (m97 structure): Y[m][n] = sum_k A[m][k]*W[n][k].
// Tile 128x128, BK=32; 4 waves, each a 64x64 quadrant (4x4 16x16x32 MFMAs).
// Staging: global_load_lds width=16, XOR chunk swizzle -> conflict-free
// ds_read_b128. blockIdx.z selects (A,W,Y) triple. mode 0: f16 Y; 2: fp32+bias.
// ---------------------------------------------------------------------------
__global__ __launch_bounds__(256, 3)
void gemm_f16nt(const _Float16* __restrict__ A0, const _Float16* __restrict__ A1,
                const _Float16* __restrict__ A2,
                const _Float16* __restrict__ W0, const _Float16* __restrict__ W1,
                const _Float16* __restrict__ W2,
                _Float16* __restrict__ Y0, _Float16* __restrict__ Y1,
                _Float16* __restrict__ Y2,
                float* __restrict__ Yf, const float* __restrict__ bias,
                int K, int N, int mode) {
  __shared__ _Float16 sA[128 * 32];
  __shared__ _Float16 sW[128 * 32];

  const int tid  = threadIdx.x;
  const int lane = tid & 63;
  const int w    = tid >> 6;
  const int l15  = lane & 15;
  const int quad = lane >> 4;
  const int z    = blockIdx.z;
  const _Float16* A = (z == 0) ? A0 : (z == 1) ? A1 : A2;
  const _Float16* W = (z == 0) ? W0 : (z == 1) ? W1 : W2;
  _Float16*       Y = (z == 0) ? Y0 : (z == 1) ? Y1 : Y2;

  const int m0 = blockIdx.y * 128;
  const int n0 = blockIdx.x * 128;

  const int Rb  = lane >> 2;
  const int pch = lane & 3;
  const int lch = pch ^ ((Rb >> 1) & 3);
  const int swr = (l15 >> 1) & 3;

  f32x4 acc[4][4];
#pragma unroll
  for (int mt = 0; mt < 4; ++mt)
#pragma unroll
    for (int nt = 0; nt < 4; ++nt)
      acc[mt][nt] = (f32x4){0.f, 0.f, 0.f, 0.f};

  const int wm = (w >> 1) * 64;
  const int wn = (w & 1) * 64;

  for (int k0 = 0; k0 < K; k0 += 32) {
    __syncthreads();
#pragma unroll
    for (int j = 0; j < 2; ++j) {
      const int seg = w * 32 + j * 16;
      gload16(A + (size_t)(m0 + seg + Rb) * K + k0 + lch * 8, &sA[seg * 32]);
      gload16(W + (size_t)(n0 + seg + Rb) * K + k0 + lch * 8, &sW[seg * 32]);
    }
    __syncthreads();

    half8 af[4], wf[4];
#pragma unroll
    for (int mt = 0; mt < 4; ++mt) {
      const int R = wm + mt * 16 + l15;
      af[mt] = *(const half8*)&sA[R * 32 + (quad ^ swr) * 8];
    }
#pragma unroll
    for (int nt = 0; nt < 4; ++nt) {
      const int R = wn + nt * 16 + l15;
      wf[nt] = *(const half8*)&sW[R * 32 + (quad ^ swr) * 8];
    }
#pragma unroll
    for (int mt = 0; mt < 4; ++mt)
#pragma unroll
      for (int nt = 0; nt < 4; ++nt)
        acc[mt][nt] = __builtin_amdgcn_mfma_f32_16x16x32_f16(wf[nt], af[mt], acc[mt][nt], 0, 0, 0);
  }

#pragma unroll
  for (int mt = 0; mt < 4; ++mt)
#pragma unroll
    for (int nt = 0; nt < 4; ++nt) {
      const int m = m0 + wm + mt * 16 + l15;
      const int n = n0 + wn + nt * 16 + quad * 4;
      if (mode == 2) {
        float4 v;
        v.x = acc[mt][nt][0] + bias[n + 0];
        v.y = acc[mt][nt][1] + bias[n + 1];
        v.z = acc[mt][nt][2] + bias[n + 2];
        v.w = acc[mt][nt][3] + bias[n + 3];
        *(float4*)(Yf + (size_t)m * N + n) = v;
      } else {
        half4 hv;
#pragma unroll
        for (int r = 0; r < 4; ++r) hv[r] = (_Float16)acc[mt][nt][r];
        *(half4*)(Y + (size_t)m * N + n) = hv;
      }
    }
}

// ---------------------------------------------------------------------------
// V pretranspose: Vh[b][t][c] -> Vt[b][h][kt][d][k16]  (f16, 8 MB)
// ---------------------------------------------------------------------------
__global__ __launch_bounds__(256)
void transpose_v(const _Float16* __restrict__ Vh, _Float16* __restrict__ Vt) {
  constexpr int PAD = 1028;
  __shared__ _Float16 tile[16][PAD];
  const int b  = blockIdx.x >> 7;
  const int kt = blockIdx.x & 127;
  const int tid = threadIdx.x;

#pragma unroll
  for (int j = 0; j < 8; ++j) {
    const int ch = tid + 256 * j;
    const int t  = ch >> 7;
    const int c8 = ch & 127;
    *(half8*)&tile[t][c8 * 8] =
        *(const half8*)(Vh + ((size_t)b * T_ + kt * 16 + t) * C_ + c8 * 8);
  }
  __syncthreads();

#pragma unroll
  for (int j = 0; j < 8; ++j) {
    const int cc = tid + 256 * j;
    const int h  = cc >> 7;
    const int d  = (cc >> 1) & 63;
    const int th = (cc & 1) * 8;
    half8 v;
#pragma unroll
    for (int i = 0; i < 8; ++i) v[i] = tile[th + i][h * 64 + d];
    *(half8*)(Vt + ((((size_t)b * H_ + h) * 128 + kt) * 64 + d) * 16 + th) = v;
  }
}

// ---------------------------------------------------------------------------
// MFMA head-softmax attention v5: identical to v4 except occupancy —
// VGPR_Count=92 fits 4 waves/SIMD; the (256,2) bound was the only cap.
// ---------------------------------------------------------------------------
__global__ __launch_bounds__(256, 4)
void attn_mfma(const _Float16* __restrict__ Qhp, const _Float16* __restrict__ Khp,
               const _Float16* __restrict__ Vtp, _Float16* __restrict__ OP,
               int nsplit) {
  __shared__ f32x4 red[2][2][4][64];

  const int tid  = threadIdx.x;
  const int lane = tid & 63;
  const int w    = tid >> 6;
  const int l15  = lane & 15;
  const int quad = lane >> 4;
  const int cell = quad * 16 + l15;

  const int nbq   = B_ * (T_ / 16);
  const int split = blockIdx.x / nbq;
  const int bq    = blockIdx.x % nbq;
  const int b  = bq >> 7;
  const int q0 = (bq & 127) << 4;

  const size_t qrow = ((size_t)b * T_ + q0 + l15) * C_;

  half8 qh[4][2];
#pragma unroll
  for (int hl = 0; hl < 4; ++hl)
#pragma unroll
    for (int kk = 0; kk < 2; ++kk)
      qh[hl][kk] = *(const half8*)(Qhp + qrow + (w * 4 + hl) * 64 + kk * 32 + quad * 8);

  f32x4 oacc[4][4];
#pragma unroll
  for (int hl = 0; hl < 4; ++hl)
#pragma unroll
    for (int mt = 0; mt < 4; ++mt)
      oacc[hl][mt] = (f32x4){0.f, 0.f, 0.f, 0.f};

  const int kpb  = T_ / nsplit;
  const int k_lo = split * kpb;
  const int jt   = kpb / 16;

  for (int j = 0; j < jt; ++j) {
    const int k0 = k_lo + j * 16;
    const int p  = j & 1;
    const int kt = k0 >> 4;
    const size_t krow = ((size_t)b * T_ + k0 + l15) * C_;

    half8 akh[4][2];
    half4 avf[4][4];
#pragma unroll
    for (int hl = 0; hl < 4; ++hl)
#pragma unroll
      for (int kk = 0; kk < 2; ++kk)
        akh[hl][kk] = *(const half8*)(Khp + krow + (w * 4 + hl) * 64 + kk * 32 + quad * 8);
#pragma unroll
    for (int hl = 0; hl < 4; ++hl) {
      const _Float16* vb =
          Vtp + (((size_t)b * H_ + (w * 4 + hl)) * 128 + kt) * 1024;
#pragma unroll
      for (int mt = 0; mt < 4; ++mt)
        avf[hl][mt] = *(const half4*)(vb + (mt * 16 + l15) * 16 + quad * 4);
    }

    f32x4 s[4];
#pragma unroll
    for (int hl = 0; hl < 4; ++hl) s[hl] = (f32x4){0.f, 0.f, 0.f, 0.f};
#pragma unroll
    for (int hl = 0; hl < 4; ++hl)
#pragma unroll
      for (int kk = 0; kk < 2; ++kk)
        s[hl] = __builtin_amdgcn_mfma_f32_16x16x32_f16(akh[hl][kk], qh[hl][kk], s[hl], 0, 0, 0);
#pragma unroll
    for (int hl = 0; hl < 4; ++hl) s[hl] = s[hl] * 8.f;

    red[p][0][w][cell] = vmax4(vmax4(s[0], s[1]), vmax4(s[2], s[3]));
    __syncthreads();
    const f32x4 gmax = vmax4(vmax4(red[p][0][0][cell], red[p][0][1][cell]),
                             vmax4(red[p][0][2][cell], red[p][0][3][cell]));
    float e[4][4];
    f32x4 ps = (f32x4){0.f, 0.f, 0.f, 0.f};
#pragma unroll
    for (int hl = 0; hl < 4; ++hl)
#pragma unroll
      for (int r = 0; r < 4; ++r) {
        e[hl][r] = __expf(s[hl][r] - gmax[r]);
        ps[r] += e[hl][r];
      }
    red[p][1][w][cell] = ps;
    __syncthreads();
    const f32x4 gs = red[p][1][0][cell] + red[p][1][1][cell] +
                     red[p][1][2][cell] + red[p][1][3][cell];
    f32x4 inv;
#pragma unroll
    for (int r = 0; r < 4; ++r) inv[r] = 1.f / gs[r];

    half4 pf[4];
#pragma unroll
    for (int hl = 0; hl < 4; ++hl)
#pragma unroll
      for (int r = 0; r < 4; ++r)
        pf[hl][r] = (_Float16)(e[hl][r] * inv[r]);

#pragma unroll
    for (int hl = 0; hl < 4; ++hl)
#pragma unroll
      for (int mt = 0; mt < 4; ++mt)
        oacc[hl][mt] =
            __builtin_amdgcn_mfma_f32_16x16x16f16(avf[hl][mt], pf[hl], oacc[hl][mt], 0, 0, 0);
  }

  _Float16* op = OP + (size_t)split * ((size_t)B_ * T_ * C_);
  const size_t orow = ((size_t)b * T_ + q0 + l15) * C_;
#pragma unroll
  for (int hl = 0; hl < 4; ++hl)
#pragma unroll
    for (int mt = 0; mt < 4; ++mt) {
      half4 hv;
#pragma unroll
      for (int r = 0; r < 4; ++r) hv[r] = (_Float16)oacc[hl][mt][r];
      *(half4*)(op + orow + (w * 4 + hl) * 64 + mt * 16 + quad * 4) = hv;
    }
}

// ---------------------------------------------------------------------------
// AOh = (f16) sum over splits of f16 OP[s]  (fp32 accumulate)
// ---------------------------------------------------------------------------
__global__ __launch_bounds__(256)
void reduce_oh(const _Float16* __restrict__ OP, _Float16* __restrict__ AOh,
               int nsplit, size_t n) {
  const size_t i = ((size_t)blockIdx.x * 256 + threadIdx.x) * 8;
  float a[8] = {};
  for (int s = 0; s < nsplit; ++s) {
    const half8 v = *(const half8*)(OP + (size_t)s * n + i);
#pragma unroll
    for (int r = 0; r < 8; ++r) a[r] += (float)v[r];
  }
  half8 o;
#pragma unroll
  for (int r = 0; r < 8; ++r) o[r] = (_Float16)a[r];
  *(half8*)(AOh + i) = o;
}

}  // namespace

extern "C" void kernel_launch(void* const* d_in, const int* in_sizes, int n_in,
                              void* d_out, int out_size, void* d_ws, size_t ws_size,
                              hipStream_t stream) {
  const float* xq = (const float*)d_in[0];
  const float* xk = (const float*)d_in[1];
  const float* xv = (const float*)d_in[2];
  const float* Wq = (const float*)d_in[3];
  const float* Wk = (const float*)d_in[4];
  const float* Wv = (const float*)d_in[5];
  const float* Wo = (const float*)d_in[6];
  const float* bo = (const float*)d_in[7];
  float* out = (float*)d_out;

  const size_t MB   = 1ull << 20;
  const size_t nBTC = (size_t)B_ * T_ * C_;  // 4M elements

  // workspace (MB):
  //  [0,8) Qh  [8,16) Kh  [16,24) Vt  [24,32) vh (pre-transpose; AOh after attn)
  //  [32,40) xqh [40,48) xkh [48,56) xvh   (dead after proj)
  //  attn: OP f16 partials [32,64)  (nsplit=4)
  //  [64,66) Wqh [66,68) Wkh [68,70) Wvh [70,72) Woh
  char* wsb = (char*)d_ws;
  _Float16* Qh  = (_Float16*)(wsb + 0 * MB);
  _Float16* Kh  = (_Float16*)(wsb + 8 * MB);
  _Float16* Vt  = (_Float16*)(wsb + 16 * MB);
  _Float16* vh  = (_Float16*)(wsb + 24 * MB);
  _Float16* AOh = (_Float16*)(wsb + 24 * MB);
  _Float16* xqh = (_Float16*)(wsb + 32 * MB);
  _Float16* xkh = (_Float16*)(wsb + 40 * MB);
  _Float16* xvh = (_Float16*)(wsb + 48 * MB);
  _Float16* OP  = (_Float16*)(wsb + 32 * MB);
  _Float16* Wqh = (_Float16*)(wsb + 64 * MB);
  _Float16* Wkh = (_Float16*)(wsb + 66 * MB);
  _Float16* Wvh = (_Float16*)(wsb + 68 * MB);
  _Float16* Woh = (_Float16*)(wsb + 70 * MB);

  const int nsplit = 4;
  const int M = B_ * T_;                     // 4096
  dim3 blk(256);

  // 1) cast all 7 fp32 inputs to f16 (16M elements)
  cast7<<<dim3(8192), blk, 0, stream>>>(xq, xk, xv, Wq, Wk, Wv, Wo,
                                        xqh, xkh, xvh, Wqh, Wkh, Wvh, Woh);

  // 2) three projections, z-batched (768 blocks = 3/CU)
  gemm_f16nt<<<dim3(C_ / 128, M / 128, 3), blk, 0, stream>>>(
      xqh, xkh, xvh, Wqh, Wkh, Wvh, Qh, Kh, vh,
      nullptr, nullptr, C_, C_, 0);

  // 3) V pretranspose
  transpose_v<<<dim3(B_ * 128), blk, 0, stream>>>(vh, Vt);

  // 4) fused head-softmax attention (split-k x4, 1024 blocks = 4/CU)
  attn_mfma<<<dim3(B_ * (T_ / 16) * nsplit), blk, 0, stream>>>(Qh, Kh, Vt, OP, nsplit);

  // 5) split reduction -> f16 AO
  reduce_oh<<<dim3((unsigned)(nBTC / 2048)), blk, 0, stream>>>(OP, AOh, nsplit, nBTC);

  // 6) output projection + bias -> fp32 out
  gemm_f16nt<<<dim3(C_ / 128, M / 128, 1), blk, 0, stream>>>(
      AOh, nullptr, nullptr, Woh, nullptr, nullptr, nullptr, nullptr, nullptr,
      out, bo, C_, C_, 2);
}